// Round 1
// baseline (233.123 us; speedup 1.0000x reference)
//
#include <hip/hip_runtime.h>
#include <hip/hip_bf16.h>
#include <math.h>

#define N_TOK 2048
#define FEAT  768
#define HEADS 12
#define DHEAD 64

typedef __bf16 v8bf __attribute__((ext_vector_type(8)));
typedef __bf16 v4bf __attribute__((ext_vector_type(4)));
typedef __bf16 v2bf __attribute__((ext_vector_type(2)));
typedef float  v4f  __attribute__((ext_vector_type(4)));

// ---------------------------------------------------------------- convert
__global__ void cvt_f32_bf16(const float* __restrict__ in, __bf16* __restrict__ out, int n) {
    int i = (blockIdx.x * blockDim.x + threadIdx.x) * 4;
    if (i < n) {
        float4 v = *(const float4*)(in + i);
        v4bf o;
        o[0] = (__bf16)v.x; o[1] = (__bf16)v.y; o[2] = (__bf16)v.z; o[3] = (__bf16)v.w;
        *(v4bf*)(out + i) = o;
    }
}

// ---------------------------------------------------------------- GEMM NT
// C[M,N] = A[M,K] . B[N,K]^T   (dot of rows — matches MFMA A/B frag layout)
// RESID=false: write bf16 to Cb.  RESID=true: write fp32 Cf = acc + resid.
template <bool RESID>
__global__ __launch_bounds__(256) void gemm_nt(
        const __bf16* __restrict__ A, const __bf16* __restrict__ B,
        __bf16* __restrict__ Cb, float* __restrict__ Cf,
        const float* __restrict__ resid, int M, int N, int K) {
    __shared__ __bf16 As[64][40];   // +8 pad keeps 16B-aligned rows, breaks conflicts
    __shared__ __bf16 Bs[64][40];
    const int t    = threadIdx.x;
    const int lane = t & 63, w = t >> 6;
    const int quad = lane >> 4, l15 = lane & 15;
    const int wm = w & 1, wn = w >> 1;          // 4 waves: 2x2 of 32x32
    const int bm = blockIdx.y * 64, bn = blockIdx.x * 64;
    const int lr = t >> 2, lc = (t & 3) * 8;    // staging: 64 rows x 32 cols, 16B/thread

    v4f acc[2][2] = {};
    for (int k0 = 0; k0 < K; k0 += 32) {
        *(float4*)&As[lr][lc] = *(const float4*)(A + (size_t)(bm + lr) * K + k0 + lc);
        *(float4*)&Bs[lr][lc] = *(const float4*)(B + (size_t)(bn + lr) * K + k0 + lc);
        __syncthreads();
        v8bf a[2], b[2];
        a[0] = *(const v8bf*)&As[wm * 32 +      l15][quad * 8];
        a[1] = *(const v8bf*)&As[wm * 32 + 16 + l15][quad * 8];
        b[0] = *(const v8bf*)&Bs[wn * 32 +      l15][quad * 8];
        b[1] = *(const v8bf*)&Bs[wn * 32 + 16 + l15][quad * 8];
#pragma unroll
        for (int mi = 0; mi < 2; mi++)
#pragma unroll
            for (int ni = 0; ni < 2; ni++)
                acc[mi][ni] = __builtin_amdgcn_mfma_f32_16x16x32_bf16(a[mi], b[ni], acc[mi][ni], 0, 0, 0);
        __syncthreads();
    }
#pragma unroll
    for (int mi = 0; mi < 2; mi++)
#pragma unroll
        for (int ni = 0; ni < 2; ni++) {
            int col = bn + wn * 32 + ni * 16 + l15;
#pragma unroll
            for (int r = 0; r < 4; r++) {
                int row = bm + wm * 32 + mi * 16 + quad * 4 + r;   // C/D: row=quad*4+reg, col=lane&15
                float v = acc[mi][ni][r];
                if (RESID) Cf[(size_t)row * N + col] = v + resid[(size_t)row * N + col];
                else       Cb[(size_t)row * N + col] = (__bf16)v;
            }
        }
}

// ---------------------------------------------------------------- attention
// One block per (head, 64 Q-rows). Flash-style online softmax over KV tiles of 64.
__global__ __launch_bounds__(256) void attention(
        const __bf16* __restrict__ Q, const __bf16* __restrict__ K,
        const __bf16* __restrict__ V, __bf16* __restrict__ O) {
    __shared__ __bf16 Vt[64][72];   // V transposed: Vt[d][kv]
    __shared__ __bf16 P [64][72];   // probabilities, A-operand staging
    const int t    = threadIdx.x;
    const int lane = t & 63, w = t >> 6;
    const int quad = lane >> 4, l15 = lane & 15;
    const int h  = blockIdx.y;
    const int q0 = blockIdx.x * 64;
    const int qrow = q0 + w * 16 + l15;          // A-frag row (m = lane&15)

    // Q fragments (d = 0..63 in two K=32 steps), loaded once
    const __bf16* qp = Q + (size_t)qrow * FEAT + h * DHEAD + quad * 8;
    v8bf qf0 = *(const v8bf*)qp;
    v8bf qf1 = *(const v8bf*)(qp + 32);

    v4f o_acc[4] = {};
    float m_r[4], l_r[4];
#pragma unroll
    for (int r = 0; r < 4; r++) { m_r[r] = -INFINITY; l_r[r] = 0.f; }

    const int vc = t & 7, vr2 = t >> 3;          // V staging: 8 d-chunks x 32 kv-pairs

    for (int kv0 = 0; kv0 < N_TOK; kv0 += 64) {
        // ---- S = Q K^T / sqrt(d)  (K frags direct from global: rows dotted)
        v4f s[4];
#pragma unroll
        for (int nt = 0; nt < 4; nt++) {
            const __bf16* kp = K + (size_t)(kv0 + nt * 16 + l15) * FEAT + h * DHEAD + quad * 8;
            v8bf kf0 = *(const v8bf*)kp;
            v8bf kf1 = *(const v8bf*)(kp + 32);
            v4f a = {};
            a = __builtin_amdgcn_mfma_f32_16x16x32_bf16(qf0, kf0, a, 0, 0, 0);
            a = __builtin_amdgcn_mfma_f32_16x16x32_bf16(qf1, kf1, a, 0, 0, 0);
            s[nt] = a;
        }
        // ---- online softmax; row r lives at q = quad*4+r, cols = nt*16 + l15
        float pv[4][4];
#pragma unroll
        for (int r = 0; r < 4; r++) {
            float s0 = s[0][r] * 0.125f, s1 = s[1][r] * 0.125f;
            float s2 = s[2][r] * 0.125f, s3 = s[3][r] * 0.125f;
            float cur = fmaxf(fmaxf(s0, s1), fmaxf(s2, s3));
            cur = fmaxf(cur, __shfl_xor(cur, 1));
            cur = fmaxf(cur, __shfl_xor(cur, 2));
            cur = fmaxf(cur, __shfl_xor(cur, 4));
            cur = fmaxf(cur, __shfl_xor(cur, 8));
            float m_new = fmaxf(m_r[r], cur);
            float alpha = __expf(m_r[r] - m_new);
            float p0 = __expf(s0 - m_new), p1 = __expf(s1 - m_new);
            float p2 = __expf(s2 - m_new), p3 = __expf(s3 - m_new);
            float rs = p0 + p1 + p2 + p3;
            rs += __shfl_xor(rs, 1);
            rs += __shfl_xor(rs, 2);
            rs += __shfl_xor(rs, 4);
            rs += __shfl_xor(rs, 8);
            l_r[r] = l_r[r] * alpha + rs;
            m_r[r] = m_new;
            pv[0][r] = p0; pv[1][r] = p1; pv[2][r] = p2; pv[3][r] = p3;
#pragma unroll
            for (int dt = 0; dt < 4; dt++) o_acc[dt][r] *= alpha;
        }
        // ---- stage V^T and P into LDS
        __syncthreads();   // prior iteration's Vt/P reads complete
        {
            const __bf16* vb = V + (size_t)(kv0 + 2 * vr2) * FEAT + h * DHEAD + vc * 8;
            v8bf v0 = *(const v8bf*)vb;
            v8bf v1 = *(const v8bf*)(vb + FEAT);
#pragma unroll
            for (int jj = 0; jj < 8; jj++) {
                int j = (jj + vc) & 7;            // stagger to dodge bank conflicts
                int d = vc * 8 + j;
                v2bf pr; pr[0] = v0[j]; pr[1] = v1[j];
                *(v2bf*)&Vt[d][2 * vr2] = pr;
            }
        }
#pragma unroll
        for (int nt = 0; nt < 4; nt++)
#pragma unroll
            for (int r = 0; r < 4; r++)
                P[w * 16 + quad * 4 + r][nt * 16 + l15] = (__bf16)pv[nt][r];
        __syncthreads();
        // ---- O += P V   (A = P from LDS, B = V via Vt rows)
#pragma unroll
        for (int ks = 0; ks < 2; ks++) {
            v8bf pa = *(const v8bf*)&P[w * 16 + l15][ks * 32 + quad * 8];
#pragma unroll
            for (int dt = 0; dt < 4; dt++) {
                v8bf vb = *(const v8bf*)&Vt[dt * 16 + l15][ks * 32 + quad * 8];
                o_acc[dt] = __builtin_amdgcn_mfma_f32_16x16x32_bf16(pa, vb, o_acc[dt], 0, 0, 0);
            }
        }
    }
    // ---- normalize and store (C/D: row=quad*4+r -> q, col=l15 -> d)
#pragma unroll
    for (int dt = 0; dt < 4; dt++)
#pragma unroll
        for (int r = 0; r < 4; r++) {
            float v = o_acc[dt][r] / l_r[r];
            O[(size_t)(q0 + w * 16 + quad * 4 + r) * FEAT + h * DHEAD + dt * 16 + l15] = (__bf16)v;
        }
}

// ---------------------------------------------------------------- layernorm
__global__ __launch_bounds__(256) void ln_kernel(
        const float* __restrict__ Y, const float* __restrict__ gamma,
        const float* __restrict__ beta, float* __restrict__ out) {
    __shared__ float sbuf[4];
    const int row = blockIdx.x, t = threadIdx.x;
    const float* y = Y + (size_t)row * FEAT;
    float v0 = y[t], v1 = y[t + 256], v2 = y[t + 512];
    float s = v0 + v1 + v2;
#pragma unroll
    for (int m = 32; m; m >>= 1) s += __shfl_xor(s, m);
    if ((t & 63) == 0) sbuf[t >> 6] = s;
    __syncthreads();
    float mean = (sbuf[0] + sbuf[1] + sbuf[2] + sbuf[3]) * (1.f / FEAT);
    __syncthreads();
    float d0 = v0 - mean, d1 = v1 - mean, d2 = v2 - mean;
    float q = d0 * d0 + d1 * d1 + d2 * d2;
#pragma unroll
    for (int m = 32; m; m >>= 1) q += __shfl_xor(q, m);
    if ((t & 63) == 0) sbuf[t >> 6] = q;
    __syncthreads();
    float var = (sbuf[0] + sbuf[1] + sbuf[2] + sbuf[3]) * (1.f / FEAT);
    float rs = rsqrtf(var + 1e-12f);
    float* o = out + (size_t)row * FEAT;
    o[t]       = d0 * rs * gamma[t]       + beta[t];
    o[t + 256] = d1 * rs * gamma[t + 256] + beta[t + 256];
    o[t + 512] = d2 * rs * gamma[t + 512] + beta[t + 512];
}

// ---------------------------------------------------------------- launch
extern "C" void kernel_launch(void* const* d_in, const int* in_sizes, int n_in,
                              void* d_out, int out_size, void* d_ws, size_t ws_size,
                              hipStream_t stream) {
    const float* x     = (const float*)d_in[0];
    const float* Wq    = (const float*)d_in[1];
    const float* Wk    = (const float*)d_in[2];
    const float* Wv    = (const float*)d_in[3];
    const float* Wo    = (const float*)d_in[4];
    const float* gamma = (const float*)d_in[5];
    const float* beta  = (const float*)d_in[6];
    float* out = (float*)d_out;

    char* ws = (char*)d_ws;
    size_t off = 0;
    auto alloc = [&](size_t bytes) -> void* {
        void* p = ws + off;
        off += (bytes + 255) & ~(size_t)255;
        return p;
    };
    const size_t XE = (size_t)N_TOK * FEAT;   // 1572864
    const size_t WE = (size_t)FEAT * FEAT;    //  589824
    __bf16* xb  = (__bf16*)alloc(XE * 2);
    __bf16* wqb = (__bf16*)alloc(WE * 2);
    __bf16* wkb = (__bf16*)alloc(WE * 2);
    __bf16* wvb = (__bf16*)alloc(WE * 2);
    __bf16* wob = (__bf16*)alloc(WE * 2);
    __bf16* Qb  = (__bf16*)alloc(XE * 2);
    __bf16* Kb  = (__bf16*)alloc(XE * 2);
    __bf16* Vb  = (__bf16*)alloc(XE * 2);
    __bf16* Ob  = (__bf16*)alloc(XE * 2);
    float*  Yf  = (float*)alloc(XE * 4);

    cvt_f32_bf16<<<(int)(XE / 4 / 256), 256, 0, stream>>>(x,  xb,  (int)XE);
    cvt_f32_bf16<<<(int)(WE / 4 / 256), 256, 0, stream>>>(Wq, wqb, (int)WE);
    cvt_f32_bf16<<<(int)(WE / 4 / 256), 256, 0, stream>>>(Wk, wkb, (int)WE);
    cvt_f32_bf16<<<(int)(WE / 4 / 256), 256, 0, stream>>>(Wv, wvb, (int)WE);
    cvt_f32_bf16<<<(int)(WE / 4 / 256), 256, 0, stream>>>(Wo, wob, (int)WE);

    dim3 ggrid(FEAT / 64, N_TOK / 64);   // (12, 32)
    gemm_nt<false><<<ggrid, 256, 0, stream>>>(xb, wqb, Qb, nullptr, nullptr, N_TOK, FEAT, FEAT);
    gemm_nt<false><<<ggrid, 256, 0, stream>>>(xb, wkb, Kb, nullptr, nullptr, N_TOK, FEAT, FEAT);
    gemm_nt<false><<<ggrid, 256, 0, stream>>>(xb, wvb, Vb, nullptr, nullptr, N_TOK, FEAT, FEAT);

    attention<<<dim3(N_TOK / 64, HEADS), 256, 0, stream>>>(Qb, Kb, Vb, Ob);

    gemm_nt<true><<<ggrid, 256, 0, stream>>>(Ob, wob, nullptr, Yf, x, N_TOK, FEAT, FEAT);

    ln_kernel<<<N_TOK, 256, 0, stream>>>(Yf, gamma, beta, out);
}

// Round 2
// 181.228 us; speedup vs baseline: 1.2864x; 1.2864x over previous
//
#include <hip/hip_runtime.h>
#include <hip/hip_bf16.h>
#include <math.h>

#define N_TOK 2048
#define FEAT  768
#define HEADS 12
#define DHEAD 64
#define SPLIT 2
#define KV_PER (N_TOK / SPLIT)

typedef __bf16 v8bf __attribute__((ext_vector_type(8)));
typedef __bf16 v4bf __attribute__((ext_vector_type(4)));
typedef __bf16 v2bf __attribute__((ext_vector_type(2)));
typedef float  v4f  __attribute__((ext_vector_type(4)));

#define XE ((size_t)N_TOK * FEAT)   // 1572864
#define WE ((size_t)FEAT * FEAT)    //  589824
#define QKV_LD (3 * FEAT)           // 2304, row stride of fused QKV output

// fold (1/sqrt(64)) * log2(e) into Wq so softmax is a bare exp2
#define SCALE_FOLD 0.18033688011112042f

// ---------------------------------------------------------------- convert (all 5 tensors, 1 launch)
__global__ __launch_bounds__(256) void cvt_all(
        const float* __restrict__ x,  const float* __restrict__ Wq,
        const float* __restrict__ Wk, const float* __restrict__ Wv,
        const float* __restrict__ Wo,
        __bf16* __restrict__ xb, __bf16* __restrict__ wqkv, __bf16* __restrict__ wob) {
    size_t i = ((size_t)blockIdx.x * 256 + threadIdx.x) * 4;
    const float* src; __bf16* dst; size_t off; float scale = 1.f;
    if (i < XE)               { src = x;  dst = xb;          off = i; }
    else if (i < XE + WE)     { src = Wq; dst = wqkv;        off = i - XE; scale = SCALE_FOLD; }
    else if (i < XE + 2 * WE) { src = Wk; dst = wqkv + WE;   off = i - XE - WE; }
    else if (i < XE + 3 * WE) { src = Wv; dst = wqkv + 2*WE; off = i - XE - 2*WE; }
    else                      { src = Wo; dst = wob;         off = i - XE - 3*WE; }
    float4 v = *(const float4*)(src + off);
    v4bf o;
    o[0] = (__bf16)(v.x * scale); o[1] = (__bf16)(v.y * scale);
    o[2] = (__bf16)(v.z * scale); o[3] = (__bf16)(v.w * scale);
    *(v4bf*)(dst + off) = o;
}

// ---------------------------------------------------------------- fused QKV GEMM, 128x128 tile
// C[2048][2304] = A[2048][768] . B[2304][768]^T
__global__ __launch_bounds__(256) void gemm_qkv(
        const __bf16* __restrict__ A, const __bf16* __restrict__ B, __bf16* __restrict__ C) {
    __shared__ __bf16 As[128][40];
    __shared__ __bf16 Bs[128][40];
    const int t    = threadIdx.x;
    const int lane = t & 63, w = t >> 6;
    const int quad = lane >> 4, l15 = lane & 15;
    const int wm = w & 1, wn = w >> 1;             // 2x2 waves, each 64x64
    const int bm = blockIdx.y * 128, bn = blockIdx.x * 128;
    const int r0 = t >> 2, c0 = (t & 3) * 8;       // staging: 64 rows x 32 cols, 16B/thread, x2 rounds

    v4f acc[4][4] = {};
    for (int k0 = 0; k0 < FEAT; k0 += 32) {
        *(float4*)&As[r0     ][c0] = *(const float4*)(A + (size_t)(bm + r0     ) * FEAT + k0 + c0);
        *(float4*)&As[r0 + 64][c0] = *(const float4*)(A + (size_t)(bm + r0 + 64) * FEAT + k0 + c0);
        *(float4*)&Bs[r0     ][c0] = *(const float4*)(B + (size_t)(bn + r0     ) * FEAT + k0 + c0);
        *(float4*)&Bs[r0 + 64][c0] = *(const float4*)(B + (size_t)(bn + r0 + 64) * FEAT + k0 + c0);
        __syncthreads();
        v8bf a[4], b[4];
#pragma unroll
        for (int mi = 0; mi < 4; mi++) a[mi] = *(const v8bf*)&As[wm * 64 + mi * 16 + l15][quad * 8];
#pragma unroll
        for (int ni = 0; ni < 4; ni++) b[ni] = *(const v8bf*)&Bs[wn * 64 + ni * 16 + l15][quad * 8];
#pragma unroll
        for (int mi = 0; mi < 4; mi++)
#pragma unroll
            for (int ni = 0; ni < 4; ni++)
                acc[mi][ni] = __builtin_amdgcn_mfma_f32_16x16x32_bf16(a[mi], b[ni], acc[mi][ni], 0, 0, 0);
        __syncthreads();
    }
#pragma unroll
    for (int mi = 0; mi < 4; mi++)
#pragma unroll
        for (int ni = 0; ni < 4; ni++) {
            int col = bn + wn * 64 + ni * 16 + l15;
#pragma unroll
            for (int r = 0; r < 4; r++) {
                int row = bm + wm * 64 + mi * 16 + quad * 4 + r;
                C[(size_t)row * QKV_LD + col] = (__bf16)acc[mi][ni][r];
            }
        }
}

// ---------------------------------------------------------------- attention (KV-split, no-max softmax)
// QKV rows: [Q | K | V] at col offsets 0/768/1536, row stride 2304. Wq pre-scaled by 0.125*log2e.
__global__ __launch_bounds__(256) void attention(
        const __bf16* __restrict__ QKV, float* __restrict__ Opart, float* __restrict__ lpart) {
    __shared__ __bf16 Vt[64][68];   // V transposed: Vt[d][kv]  (68 = odd dword stride, conflict-free)
    __shared__ __bf16 P [64][68];
    const int t    = threadIdx.x;
    const int lane = t & 63, w = t >> 6;
    const int quad = lane >> 4, l15 = lane & 15;
    const int h  = blockIdx.y;
    const int q0 = blockIdx.x * 64;
    const int s  = blockIdx.z;
    const int qrow = q0 + w * 16 + l15;            // A-frag row m = lane&15

    const __bf16* qp = QKV + (size_t)qrow * QKV_LD + h * DHEAD + quad * 8;
    v8bf qf0 = *(const v8bf*)qp;
    v8bf qf1 = *(const v8bf*)(qp + 32);

    v4f o_acc[4] = {};
    float lacc[4] = {0.f, 0.f, 0.f, 0.f};

    const int vc = t & 7, vr2 = t >> 3;            // V staging

    for (int kv0 = s * KV_PER; kv0 < (s + 1) * KV_PER; kv0 += 64) {
        // ---- S = Q' K^T  (scale pre-folded)
        v4f sv[4];
#pragma unroll
        for (int nt = 0; nt < 4; nt++) {
            const __bf16* kp = QKV + (size_t)(kv0 + nt * 16 + l15) * QKV_LD + FEAT + h * DHEAD + quad * 8;
            v8bf kf0 = *(const v8bf*)kp;
            v8bf kf1 = *(const v8bf*)(kp + 32);
            v4f a = {};
            a = __builtin_amdgcn_mfma_f32_16x16x32_bf16(qf0, kf0, a, 0, 0, 0);
            a = __builtin_amdgcn_mfma_f32_16x16x32_bf16(qf1, kf1, a, 0, 0, 0);
            sv[nt] = a;
        }
        // ---- p = 2^s; accumulate row-sum per-lane (cross-lane reduce deferred to epilogue)
        float pv[4][4];
#pragma unroll
        for (int r = 0; r < 4; r++) {
            float p0 = exp2f(sv[0][r]), p1 = exp2f(sv[1][r]);
            float p2 = exp2f(sv[2][r]), p3 = exp2f(sv[3][r]);
            pv[0][r] = p0; pv[1][r] = p1; pv[2][r] = p2; pv[3][r] = p3;
            lacc[r] += (p0 + p1) + (p2 + p3);
        }
        // ---- stage V^T and P into LDS
        __syncthreads();   // prior iteration's Vt/P reads complete
        {
            const __bf16* vb = QKV + (size_t)(kv0 + 2 * vr2) * QKV_LD + 2 * FEAT + h * DHEAD + vc * 8;
            v8bf v0 = *(const v8bf*)vb;
            v8bf v1 = *(const v8bf*)(vb + QKV_LD);
#pragma unroll
            for (int jj = 0; jj < 8; jj++) {
                int j = (jj + vc) & 7;             // stagger
                int d = vc * 8 + j;
                v2bf pr; pr[0] = v0[j]; pr[1] = v1[j];
                *(v2bf*)&Vt[d][2 * vr2] = pr;
            }
        }
#pragma unroll
        for (int nt = 0; nt < 4; nt++)
#pragma unroll
            for (int r = 0; r < 4; r++)
                P[w * 16 + quad * 4 + r][nt * 16 + l15] = (__bf16)pv[nt][r];
        __syncthreads();
        // ---- O += P V
#pragma unroll
        for (int ks = 0; ks < 2; ks++) {
            v8bf pa = *(const v8bf*)&P[w * 16 + l15][ks * 32 + quad * 8];
#pragma unroll
            for (int dt = 0; dt < 4; dt++) {
                v8bf vb2 = *(const v8bf*)&Vt[dt * 16 + l15][ks * 32 + quad * 8];
                o_acc[dt] = __builtin_amdgcn_mfma_f32_16x16x32_bf16(pa, vb2, o_acc[dt], 0, 0, 0);
            }
        }
    }
    // ---- epilogue: reduce l across the 16 col-lanes, store unnormalized partials
    float* op = Opart + (size_t)s * (N_TOK * FEAT);
#pragma unroll
    for (int r = 0; r < 4; r++) {
        float l = lacc[r];
        l += __shfl_xor(l, 1); l += __shfl_xor(l, 2);
        l += __shfl_xor(l, 4); l += __shfl_xor(l, 8);
        int row = q0 + w * 16 + quad * 4 + r;
        if (l15 == 0) lpart[((size_t)s * HEADS + h) * N_TOK + row] = l;
#pragma unroll
        for (int dt = 0; dt < 4; dt++)
            op[(size_t)row * FEAT + h * DHEAD + dt * 16 + l15] = o_acc[dt][r];
    }
}

// ---------------------------------------------------------------- combine KV-split partials
__global__ __launch_bounds__(256) void combine(
        const float* __restrict__ Op, const float* __restrict__ lp, __bf16* __restrict__ Ob) {
    size_t i = ((size_t)blockIdx.x * 256 + threadIdx.x) * 4;
    int row = (int)(i / FEAT), col = (int)(i % FEAT), h = col >> 6;
    float l = lp[(size_t)h * N_TOK + row] + lp[(size_t)(HEADS + h) * N_TOK + row];
    float inv = 1.0f / l;
    float4 a = *(const float4*)(Op + i);
    float4 b = *(const float4*)(Op + XE + i);
    v4bf o;
    o[0] = (__bf16)((a.x + b.x) * inv); o[1] = (__bf16)((a.y + b.y) * inv);
    o[2] = (__bf16)((a.z + b.z) * inv); o[3] = (__bf16)((a.w + b.w) * inv);
    *(v4bf*)(Ob + i) = o;
}

// ---------------------------------------------------------------- output proj + residual, 64x64 tile
__global__ __launch_bounds__(256) void gemm_out(
        const __bf16* __restrict__ A, const __bf16* __restrict__ B,
        float* __restrict__ Cf, const float* __restrict__ resid) {
    __shared__ __bf16 As[64][40];
    __shared__ __bf16 Bs[64][40];
    const int t    = threadIdx.x;
    const int lane = t & 63, w = t >> 6;
    const int quad = lane >> 4, l15 = lane & 15;
    const int wm = w & 1, wn = w >> 1;
    const int bm = blockIdx.y * 64, bn = blockIdx.x * 64;
    const int lr = t >> 2, lc = (t & 3) * 8;

    v4f acc[2][2] = {};
    for (int k0 = 0; k0 < FEAT; k0 += 32) {
        *(float4*)&As[lr][lc] = *(const float4*)(A + (size_t)(bm + lr) * FEAT + k0 + lc);
        *(float4*)&Bs[lr][lc] = *(const float4*)(B + (size_t)(bn + lr) * FEAT + k0 + lc);
        __syncthreads();
        v8bf a[2], b[2];
        a[0] = *(const v8bf*)&As[wm * 32 +      l15][quad * 8];
        a[1] = *(const v8bf*)&As[wm * 32 + 16 + l15][quad * 8];
        b[0] = *(const v8bf*)&Bs[wn * 32 +      l15][quad * 8];
        b[1] = *(const v8bf*)&Bs[wn * 32 + 16 + l15][quad * 8];
#pragma unroll
        for (int mi = 0; mi < 2; mi++)
#pragma unroll
            for (int ni = 0; ni < 2; ni++)
                acc[mi][ni] = __builtin_amdgcn_mfma_f32_16x16x32_bf16(a[mi], b[ni], acc[mi][ni], 0, 0, 0);
        __syncthreads();
    }
#pragma unroll
    for (int mi = 0; mi < 2; mi++)
#pragma unroll
        for (int ni = 0; ni < 2; ni++) {
            int col = bn + wn * 32 + ni * 16 + l15;
#pragma unroll
            for (int r = 0; r < 4; r++) {
                int row = bm + wm * 32 + mi * 16 + quad * 4 + r;
                Cf[(size_t)row * FEAT + col] = acc[mi][ni][r] + resid[(size_t)row * FEAT + col];
            }
        }
}

// ---------------------------------------------------------------- layernorm
__global__ __launch_bounds__(256) void ln_kernel(
        const float* __restrict__ Y, const float* __restrict__ gamma,
        const float* __restrict__ beta, float* __restrict__ out) {
    __shared__ float sbuf[4];
    const int row = blockIdx.x, t = threadIdx.x;
    const float* y = Y + (size_t)row * FEAT;
    float v0 = y[t], v1 = y[t + 256], v2 = y[t + 512];
    float s = v0 + v1 + v2;
#pragma unroll
    for (int m = 32; m; m >>= 1) s += __shfl_xor(s, m);
    if ((t & 63) == 0) sbuf[t >> 6] = s;
    __syncthreads();
    float mean = (sbuf[0] + sbuf[1] + sbuf[2] + sbuf[3]) * (1.f / FEAT);
    __syncthreads();
    float d0 = v0 - mean, d1 = v1 - mean, d2 = v2 - mean;
    float q = d0 * d0 + d1 * d1 + d2 * d2;
#pragma unroll
    for (int m = 32; m; m >>= 1) q += __shfl_xor(q, m);
    if ((t & 63) == 0) sbuf[t >> 6] = q;
    __syncthreads();
    float var = (sbuf[0] + sbuf[1] + sbuf[2] + sbuf[3]) * (1.f / FEAT);
    float rs = rsqrtf(var + 1e-12f);
    float* o = out + (size_t)row * FEAT;
    o[t]       = d0 * rs * gamma[t]       + beta[t];
    o[t + 256] = d1 * rs * gamma[t + 256] + beta[t + 256];
    o[t + 512] = d2 * rs * gamma[t + 512] + beta[t + 512];
}

// ---------------------------------------------------------------- launch
extern "C" void kernel_launch(void* const* d_in, const int* in_sizes, int n_in,
                              void* d_out, int out_size, void* d_ws, size_t ws_size,
                              hipStream_t stream) {
    const float* x     = (const float*)d_in[0];
    const float* Wq    = (const float*)d_in[1];
    const float* Wk    = (const float*)d_in[2];
    const float* Wv    = (const float*)d_in[3];
    const float* Wo    = (const float*)d_in[4];
    const float* gamma = (const float*)d_in[5];
    const float* beta  = (const float*)d_in[6];
    float* out = (float*)d_out;

    char* ws = (char*)d_ws;
    size_t off = 0;
    auto alloc = [&](size_t bytes) -> void* {
        void* p = ws + off;
        off += (bytes + 255) & ~(size_t)255;
        return p;
    };
    __bf16* xb   = (__bf16*)alloc(XE * 2);        // dead after gemm_qkv
    __bf16* wqkv = (__bf16*)alloc(3 * WE * 2);    // dead after gemm_qkv
    __bf16* wob  = (__bf16*)alloc(WE * 2);
    __bf16* qkv  = (__bf16*)alloc(XE * 3 * 2);    // fused [Q|K|V], row stride 2304
    __bf16* Ob   = (__bf16*)alloc(XE * 2);
    float*  Op   = (float*)alloc(SPLIT * XE * 4); // unnormalized O partials
    float*  lp   = (float*)alloc(SPLIT * HEADS * N_TOK * 4);
    float*  Yf   = (float*)ws;                    // aliases xb+wqkv (both dead by then)

    cvt_all<<<(int)((XE + 4 * WE) / 4 / 256), 256, 0, stream>>>(x, Wq, Wk, Wv, Wo, xb, wqkv, wob);

    gemm_qkv<<<dim3(QKV_LD / 128, N_TOK / 128), 256, 0, stream>>>(xb, wqkv, qkv);

    attention<<<dim3(N_TOK / 64, HEADS, SPLIT), 256, 0, stream>>>(qkv, Op, lp);

    combine<<<(int)(XE / 4 / 256), 256, 0, stream>>>(Op, lp, Ob);

    gemm_out<<<dim3(FEAT / 64, N_TOK / 64), 256, 0, stream>>>(Ob, wob, Yf, x);

    ln_kernel<<<N_TOK, 256, 0, stream>>>(Yf, gamma, beta, out);
}